// Round 1
// 481.677 us; speedup vs baseline: 1.1250x; 1.1250x over previous
//
#include <hip/hip_runtime.h>

#define B_ 16384
#define E_ 1024
#define H_ 8
#define D_ 128
#define BK 32

typedef _Float16 f16;
typedef _Float16 f16x8 __attribute__((ext_vector_type(8)));
typedef float f32x4 __attribute__((ext_vector_type(4)));

// async global -> LDS, 16B per lane. LDS dest is wave-uniform base + lane*16.
__device__ __forceinline__ void gload16(const f16* g, f16* l) {
    __builtin_amdgcn_global_load_lds(
        (const __attribute__((address_space(1))) void*)g,
        (__attribute__((address_space(3))) void*)l, 16, 0, 0);
}

// ---------------- f32 -> f16 conversion ----------------
__global__ __launch_bounds__(256) void cvt_kernel(const float4* __restrict__ src,
                                                  ushort4* __restrict__ dst, int n4) {
    int i = blockIdx.x * 256 + threadIdx.x;
    if (i >= n4) return;
    float4 v = src[i];
    union { ushort4 u; f16 h[4]; } o;
    o.h[0] = (f16)v.x; o.h[1] = (f16)v.y; o.h[2] = (f16)v.z; o.h[3] = (f16)v.w;
    dst[i] = o.u;
}

// ---------------- fused single-pass QKV + 2-key attention -> ctx ----------------
// grid: (B/64, H). 256 threads = 4 waves, wave grid 2x2 over (64 rows x 128 head cols).
// One K-pass computes Q, Kimg, Ksig, Vimg, Vsig (5 accumulator sets); epilogue mixes
// ctx = a0*Vimg + a1*Vsig (softmax linearity), avoiding a second pass entirely.
__global__ __launch_bounds__(256, 2) void qkv_attn_kernel(
    const f16* __restrict__ Xi, const f16* __restrict__ Xs,
    const f16* __restrict__ Wq, const f16* __restrict__ Wk, const f16* __restrict__ Wv,
    const float* __restrict__ bq, const float* __restrict__ bk, const float* __restrict__ bv,
    f16* __restrict__ ctx)
{
    // linear LDS (row stride 32 f16 = 64B): required by global_load_lds, bank-uniform
    // for ds_read_b128 (start banks {0,16}+4*lq cover all groups evenly).
    __shared__ f16 sAi[64][BK];
    __shared__ f16 sAs[64][BK];
    __shared__ f16 sWq[128][BK];
    __shared__ f16 sWk[128][BK];
    __shared__ f16 sWv[128][BK];
    __shared__ float sdot[2][64][2];
    __shared__ float sa0[64];

    const int tid  = threadIdx.x;
    const int lane = tid & 63;
    const int wave = tid >> 6;
    const int wr = wave >> 1, wc = wave & 1;
    const int l16 = lane & 15, lq = lane >> 4;

    const int row0 = blockIdx.x * 64;
    const int col0 = blockIdx.y * D_;   // head slice in E

    // per-lane global source addressing for gload16 (lane l covers row l/4, cols (l%4)*8..+8)
    const int lr = lane >> 2;          // 0..15
    const int lc = (lane & 3) * 8;     // 0,8,16,24

    const f16* gAi = Xi + (size_t)(row0 + wave * 16 + lr) * E_ + lc;
    const f16* gAs = Xs + (size_t)(row0 + wave * 16 + lr) * E_ + lc;
    const size_t woff = (size_t)(col0 + wave * 32 + lr) * E_ + lc;
    const f16* gWq = Wq + woff;
    const f16* gWk = Wk + woff;
    const f16* gWv = Wv + woff;
    const size_t wskip = (size_t)16 * E_;

    // wave-uniform LDS destinations
    f16* lAi  = &sAi[wave * 16][0];
    f16* lAs  = &sAs[wave * 16][0];
    f16* lWq0 = &sWq[wave * 32][0];      f16* lWq1 = &sWq[wave * 32 + 16][0];
    f16* lWk0 = &sWk[wave * 32][0];      f16* lWk1 = &sWk[wave * 32 + 16][0];
    f16* lWv0 = &sWv[wave * 32][0];      f16* lWv1 = &sWv[wave * 32 + 16][0];

    f32x4 zero4 = {0.f, 0.f, 0.f, 0.f};
    f32x4 accQ[2][4], accKi[2][4], accKs[2][4], accVi[2][4], accVs[2][4];
    #pragma unroll
    for (int i = 0; i < 2; i++)
        #pragma unroll
        for (int j = 0; j < 4; j++) {
            accQ[i][j] = zero4; accKi[i][j] = zero4; accKs[i][j] = zero4;
            accVi[i][j] = zero4; accVs[i][j] = zero4;
        }

    for (int kk = 0; kk < E_; kk += BK) {
        gload16(gAi + kk, lAi);
        gload16(gAs + kk, lAs);
        gload16(gWq + kk, lWq0);
        gload16(gWq + wskip + kk, lWq1);
        gload16(gWk + kk, lWk0);
        gload16(gWk + wskip + kk, lWk1);
        gload16(gWv + kk, lWv0);
        gload16(gWv + wskip + kk, lWv1);
        __syncthreads();   // drains vmcnt -> tile resident

        f16x8 aI[2], aS[2], bF[4];
        #pragma unroll
        for (int fr = 0; fr < 2; fr++) {
            aI[fr] = *(const f16x8*)&sAi[wr * 32 + fr * 16 + l16][lq * 8];
            aS[fr] = *(const f16x8*)&sAs[wr * 32 + fr * 16 + l16][lq * 8];
        }
        // Q
        #pragma unroll
        for (int fc = 0; fc < 4; fc++)
            bF[fc] = *(const f16x8*)&sWq[wc * 64 + fc * 16 + l16][lq * 8];
        #pragma unroll
        for (int fr = 0; fr < 2; fr++)
            #pragma unroll
            for (int fc = 0; fc < 4; fc++)
                accQ[fr][fc] = __builtin_amdgcn_mfma_f32_16x16x32_f16(aI[fr], bF[fc], accQ[fr][fc], 0, 0, 0);
        // K (both modalities share B-frag)
        #pragma unroll
        for (int fc = 0; fc < 4; fc++)
            bF[fc] = *(const f16x8*)&sWk[wc * 64 + fc * 16 + l16][lq * 8];
        #pragma unroll
        for (int fr = 0; fr < 2; fr++)
            #pragma unroll
            for (int fc = 0; fc < 4; fc++) {
                accKi[fr][fc] = __builtin_amdgcn_mfma_f32_16x16x32_f16(aI[fr], bF[fc], accKi[fr][fc], 0, 0, 0);
                accKs[fr][fc] = __builtin_amdgcn_mfma_f32_16x16x32_f16(aS[fr], bF[fc], accKs[fr][fc], 0, 0, 0);
            }
        // V (both modalities share B-frag)
        #pragma unroll
        for (int fc = 0; fc < 4; fc++)
            bF[fc] = *(const f16x8*)&sWv[wc * 64 + fc * 16 + l16][lq * 8];
        #pragma unroll
        for (int fr = 0; fr < 2; fr++)
            #pragma unroll
            for (int fc = 0; fc < 4; fc++) {
                accVi[fr][fc] = __builtin_amdgcn_mfma_f32_16x16x32_f16(aI[fr], bF[fc], accVi[fr][fc], 0, 0, 0);
                accVs[fr][fc] = __builtin_amdgcn_mfma_f32_16x16x32_f16(aS[fr], bF[fc], accVs[fr][fc], 0, 0, 0);
            }
        __syncthreads();   // protect LDS tile until all waves done reading
    }

    // biases on score paths (zero in practice but correct in general)
    #pragma unroll
    for (int fc = 0; fc < 4; fc++) {
        int col = col0 + wc * 64 + fc * 16 + l16;
        float bqv = bq[col], bkv = bk[col];
        #pragma unroll
        for (int fr = 0; fr < 2; fr++)
            #pragma unroll
            for (int e = 0; e < 4; e++) {
                accQ[fr][fc][e]  += bqv;
                accKi[fr][fc][e] += bkv;
                accKs[fr][fc][e] += bkv;
            }
    }

    // scores: per-row dot(q,k) over this head's 128 cols
    // C layout: col = lane&15, row = (lane>>4)*4 + e (within 16x16 frag)
    #pragma unroll
    for (int fr = 0; fr < 2; fr++)
        #pragma unroll
        for (int e = 0; e < 4; e++) {
            float d0 = 0.f, d1 = 0.f;
            #pragma unroll
            for (int fc = 0; fc < 4; fc++) {
                d0 += accQ[fr][fc][e] * accKi[fr][fc][e];
                d1 += accQ[fr][fc][e] * accKs[fr][fc][e];
            }
            #pragma unroll
            for (int m = 1; m < 16; m <<= 1) {
                d0 += __shfl_xor(d0, m, 64);
                d1 += __shfl_xor(d1, m, 64);
            }
            if (l16 == 0) {
                int row = wr * 32 + fr * 16 + lq * 4 + e;
                sdot[0][row][wc] = d0;
                sdot[1][row][wc] = d1;
            }
        }
    __syncthreads();
    if (tid < 64) {
        const float scale = 0.088388347648318447f;  // 1/sqrt(128)
        float s0 = (sdot[0][tid][0] + sdot[0][tid][1]) * scale;
        float s1 = (sdot[1][tid][0] + sdot[1][tid][1]) * scale;
        sa0[tid] = 1.0f / (1.0f + expf(s1 - s0));
    }
    __syncthreads();

    // ctx = a0*Vimg + a1*Vsig + bv, written f16
    #pragma unroll
    for (int fc = 0; fc < 4; fc++) {
        int col = col0 + wc * 64 + fc * 16 + l16;
        float bvv = bv[col];
        #pragma unroll
        for (int fr = 0; fr < 2; fr++)
            #pragma unroll
            for (int e = 0; e < 4; e++) {
                int row = wr * 32 + fr * 16 + lq * 4 + e;
                float a0 = sa0[row];
                float v  = a0 * accVi[fr][fc][e] + (1.0f - a0) * accVs[fr][fc][e] + bvv;
                ctx[(size_t)(row0 + row) * E_ + col] = (f16)v;
            }
    }
}

// ---------------- out projection: ctx @ Wo^T + bo + residual -> f32 ----------------
// grid (B/128, E/128), 256 threads, 4 waves each 64x64 (4x4 frags). gload_lds staging.
__global__ __launch_bounds__(256) void out_proj_kernel(
    const f16* __restrict__ A, const f16* __restrict__ Wo, const float* __restrict__ bo,
    const float* __restrict__ resid, float* __restrict__ out)
{
    __shared__ f16 sA[128][BK];
    __shared__ f16 sB[128][BK];
    const int tid  = threadIdx.x;
    const int lane = tid & 63;
    const int wave = tid >> 6;
    const int wr = wave >> 1, wc = wave & 1;
    const int l16 = lane & 15, lq = lane >> 4;
    const int row0 = blockIdx.x * 128;
    const int col0 = blockIdx.y * 128;

    const int lr = lane >> 2;
    const int lc = (lane & 3) * 8;
    const f16* gA0 = A  + (size_t)(row0 + wave * 32 + lr) * E_ + lc;
    const f16* gB0 = Wo + (size_t)(col0 + wave * 32 + lr) * E_ + lc;
    const size_t wskip = (size_t)16 * E_;
    f16* lA0 = &sA[wave * 32][0];      f16* lA1 = &sA[wave * 32 + 16][0];
    f16* lB0 = &sB[wave * 32][0];      f16* lB1 = &sB[wave * 32 + 16][0];

    f32x4 zero4 = {0.f, 0.f, 0.f, 0.f};
    f32x4 acc[4][4];
    #pragma unroll
    for (int i = 0; i < 4; i++)
        #pragma unroll
        for (int j = 0; j < 4; j++) acc[i][j] = zero4;

    for (int kk = 0; kk < E_; kk += BK) {
        gload16(gA0 + kk, lA0);
        gload16(gA0 + wskip + kk, lA1);
        gload16(gB0 + kk, lB0);
        gload16(gB0 + wskip + kk, lB1);
        __syncthreads();

        f16x8 aF[4], bF[4];
        #pragma unroll
        for (int f = 0; f < 4; f++) {
            aF[f] = *(const f16x8*)&sA[wr * 64 + f * 16 + l16][lq * 8];
            bF[f] = *(const f16x8*)&sB[wc * 64 + f * 16 + l16][lq * 8];
        }
        #pragma unroll
        for (int fr = 0; fr < 4; fr++)
            #pragma unroll
            for (int fc = 0; fc < 4; fc++)
                acc[fr][fc] = __builtin_amdgcn_mfma_f32_16x16x32_f16(aF[fr], bF[fc], acc[fr][fc], 0, 0, 0);
        __syncthreads();
    }

    #pragma unroll
    for (int fc = 0; fc < 4; fc++) {
        int col = col0 + wc * 64 + fc * 16 + l16;
        float bov = bo[col];
        #pragma unroll
        for (int fr = 0; fr < 4; fr++)
            #pragma unroll
            for (int e = 0; e < 4; e++) {
                int row = row0 + wr * 64 + fr * 16 + lq * 4 + e;
                out[(size_t)row * E_ + col] = acc[fr][fc][e] + bov + resid[(size_t)row * E_ + col];
            }
    }
}

// ---------------- in-place LayerNorm over E=1024 ----------------
__global__ __launch_bounds__(256) void ln_kernel(
    float* __restrict__ x, const float* __restrict__ gamma,
    const float* __restrict__ beta, float* __restrict__ out)
{
    const int row = blockIdx.x;
    const int tid = threadIdx.x;
    const float4* xr = (const float4*)(x + (size_t)row * E_);
    float4 v = xr[tid];
    float s  = v.x + v.y + v.z + v.w;
    float s2 = v.x * v.x + v.y * v.y + v.z * v.z + v.w * v.w;
    #pragma unroll
    for (int m = 1; m < 64; m <<= 1) {
        s  += __shfl_xor(s, m, 64);
        s2 += __shfl_xor(s2, m, 64);
    }
    __shared__ float red[8];
    int wv = tid >> 6, ln = tid & 63;
    if (ln == 0) { red[wv] = s; red[4 + wv] = s2; }
    __syncthreads();
    s  = red[0] + red[1] + red[2] + red[3];
    s2 = red[4] + red[5] + red[6] + red[7];
    float mu  = s * (1.0f / E_);
    float var = s2 * (1.0f / E_) - mu * mu;
    float r   = rsqrtf(var + 1e-5f);
    float4 g  = ((const float4*)gamma)[tid];
    float4 bb = ((const float4*)beta)[tid];
    float4 o;
    o.x = (v.x - mu) * r * g.x + bb.x;
    o.y = (v.y - mu) * r * g.y + bb.y;
    o.z = (v.z - mu) * r * g.z + bb.z;
    o.w = (v.w - mu) * r * g.w + bb.w;
    ((float4*)(out + (size_t)row * E_))[tid] = o;
}

extern "C" void kernel_launch(void* const* d_in, const int* in_sizes, int n_in,
                              void* d_out, int out_size, void* d_ws, size_t ws_size,
                              hipStream_t stream)
{
    (void)in_sizes; (void)n_in; (void)out_size; (void)ws_size;
    const float* image  = (const float*)d_in[0];
    const float* signal = (const float*)d_in[1];
    const float* Wq = (const float*)d_in[2];
    const float* Wk = (const float*)d_in[3];
    const float* Wv = (const float*)d_in[4];
    const float* bq = (const float*)d_in[5];
    const float* bk = (const float*)d_in[6];
    const float* bv = (const float*)d_in[7];
    const float* Wo = (const float*)d_in[8];
    const float* bo = (const float*)d_in[9];
    const float* gamma = (const float*)d_in[10];
    const float* beta  = (const float*)d_in[11];
    float* out = (float*)d_out;

    char* ws = (char*)d_ws;
    f16* Xi16 = (f16*)(ws);                            // 32 MB
    f16* Xs16 = (f16*)(ws + 32ull * 1024 * 1024);      // 32 MB
    f16* Wq16 = (f16*)(ws + 64ull * 1024 * 1024);      // 2 MB
    f16* Wk16 = (f16*)(ws + 66ull * 1024 * 1024);      // 2 MB
    f16* Wv16 = (f16*)(ws + 68ull * 1024 * 1024);      // 2 MB
    f16* Wo16 = (f16*)(ws + 70ull * 1024 * 1024);      // 2 MB
    f16* ctx  = (f16*)(ws + 72ull * 1024 * 1024);      // 32 MB  (total 104 MB)

    const int nBE4 = B_ * E_ / 4;   // 4194304
    const int nEE4 = E_ * E_ / 4;   // 262144
    cvt_kernel<<<nBE4 / 256, 256, 0, stream>>>((const float4*)image,  (ushort4*)Xi16, nBE4);
    cvt_kernel<<<nBE4 / 256, 256, 0, stream>>>((const float4*)signal, (ushort4*)Xs16, nBE4);
    cvt_kernel<<<nEE4 / 256, 256, 0, stream>>>((const float4*)Wq, (ushort4*)Wq16, nEE4);
    cvt_kernel<<<nEE4 / 256, 256, 0, stream>>>((const float4*)Wk, (ushort4*)Wk16, nEE4);
    cvt_kernel<<<nEE4 / 256, 256, 0, stream>>>((const float4*)Wv, (ushort4*)Wv16, nEE4);
    cvt_kernel<<<nEE4 / 256, 256, 0, stream>>>((const float4*)Wo, (ushort4*)Wo16, nEE4);

    dim3 g2(B_ / 64, H_);
    qkv_attn_kernel<<<g2, 256, 0, stream>>>(Xi16, Xs16, Wq16, Wk16, Wv16, bq, bk, bv, ctx);

    dim3 g4(B_ / 128, E_ / 128);
    out_proj_kernel<<<g4, 256, 0, stream>>>(ctx, Wo16, bo, image, out);

    ln_kernel<<<B_, 256, 0, stream>>>(out, gamma, beta, out);
}

// Round 2
// 470.293 us; speedup vs baseline: 1.1522x; 1.0242x over previous
//
#include <hip/hip_runtime.h>

#define B_ 16384
#define E_ 1024
#define H_ 8
#define D_ 128
#define BK 32

typedef _Float16 f16;
typedef _Float16 f16x8 __attribute__((ext_vector_type(8)));
typedef float f32x4 __attribute__((ext_vector_type(4)));

// async global -> LDS, 16B per lane. LDS dest is wave-uniform base + lane*16.
__device__ __forceinline__ void gload16(const f16* g, f16* l) {
    __builtin_amdgcn_global_load_lds(
        (const __attribute__((address_space(1))) void*)g,
        (__attribute__((address_space(3))) void*)l, 16, 0, 0);
}

// LDS XOR swizzle (within each 16-row x 32-col f16 tile staged by one gload16):
//   LDS chunk p (16B) of row r holds global chunk p ^ ((r>>1)&3).
// Write side: lane l (r=l>>2, p=l&3) sources global chunk (l&3)^((l>>3)&3).
// Read side: global chunk lq of row r lives at LDS chunk lq^((r>>1)&3).
// Start banks across l16=0..15 become {0,16,4,20,8,24,12,28}x2 -> 2-way (free).

// ---------------- f32 -> f16 conversion ----------------
__global__ __launch_bounds__(256) void cvt2_kernel(const float4* __restrict__ s0,
                                                   const float4* __restrict__ s1,
                                                   ushort4* __restrict__ d0,
                                                   ushort4* __restrict__ d1, int n4) {
    const float4* s = blockIdx.y ? s1 : s0;
    ushort4* d = blockIdx.y ? d1 : d0;
    int i = blockIdx.x * 256 + threadIdx.x;
    if (i >= n4) return;
    float4 v = s[i];
    union { ushort4 u; f16 h[4]; } o;
    o.h[0] = (f16)v.x; o.h[1] = (f16)v.y; o.h[2] = (f16)v.z; o.h[3] = (f16)v.w;
    d[i] = o.u;
}

__global__ __launch_bounds__(256) void cvt4_kernel(
    const float4* __restrict__ s0, const float4* __restrict__ s1,
    const float4* __restrict__ s2, const float4* __restrict__ s3,
    ushort4* __restrict__ d0, ushort4* __restrict__ d1,
    ushort4* __restrict__ d2, ushort4* __restrict__ d3, int n4) {
    const float4* s; ushort4* d;
    switch (blockIdx.y) {
        case 0: s = s0; d = d0; break;
        case 1: s = s1; d = d1; break;
        case 2: s = s2; d = d2; break;
        default: s = s3; d = d3; break;
    }
    int i = blockIdx.x * 256 + threadIdx.x;
    if (i >= n4) return;
    float4 v = s[i];
    union { ushort4 u; f16 h[4]; } o;
    o.h[0] = (f16)v.x; o.h[1] = (f16)v.y; o.h[2] = (f16)v.z; o.h[3] = (f16)v.w;
    d[i] = o.u;
}

// ---------------- fused single-pass QKV + 2-key attention -> ctx ----------------
// grid: (B/64, H). 256 threads = 4 waves, wave grid 2x2 over (64 rows x 128 head cols).
// One K-pass computes Q, Kimg, Ksig, Vimg, Vsig; epilogue mixes ctx = a0*Vi + a1*Vs.
__global__ __launch_bounds__(256, 2) void qkv_attn_kernel(
    const f16* __restrict__ Xi, const f16* __restrict__ Xs,
    const f16* __restrict__ Wq, const f16* __restrict__ Wk, const f16* __restrict__ Wv,
    const float* __restrict__ bq, const float* __restrict__ bk, const float* __restrict__ bv,
    f16* __restrict__ ctx)
{
    __shared__ f16 sAi[64][BK];
    __shared__ f16 sAs[64][BK];
    __shared__ f16 sWq[128][BK];
    __shared__ f16 sWk[128][BK];
    __shared__ f16 sWv[128][BK];
    __shared__ float sdot[2][64][2];
    __shared__ float sa0[64];

    const int tid  = threadIdx.x;
    const int lane = tid & 63;
    const int wave = tid >> 6;
    const int wr = wave >> 1, wc = wave & 1;
    const int l16 = lane & 15, lq = lane >> 4;

    const int row0 = blockIdx.x * 64;
    const int col0 = blockIdx.y * D_;   // head slice in E

    // per-lane global source addressing for gload16, source column XOR-swizzled
    const int lr = lane >> 2;                                   // 0..15
    const int lc = ((lane & 3) ^ ((lane >> 3) & 3)) * 8;        // swizzled chunk
    // read-side swizzled column (rows are base16 + l16)
    const int rc = (lq ^ ((l16 >> 1) & 3)) * 8;

    const f16* gAi = Xi + (size_t)(row0 + wave * 16 + lr) * E_ + lc;
    const f16* gAs = Xs + (size_t)(row0 + wave * 16 + lr) * E_ + lc;
    const size_t woff = (size_t)(col0 + wave * 32 + lr) * E_ + lc;
    const f16* gWq = Wq + woff;
    const f16* gWk = Wk + woff;
    const f16* gWv = Wv + woff;
    const size_t wskip = (size_t)16 * E_;

    // wave-uniform LDS destinations
    f16* lAi  = &sAi[wave * 16][0];
    f16* lAs  = &sAs[wave * 16][0];
    f16* lWq0 = &sWq[wave * 32][0];      f16* lWq1 = &sWq[wave * 32 + 16][0];
    f16* lWk0 = &sWk[wave * 32][0];      f16* lWk1 = &sWk[wave * 32 + 16][0];
    f16* lWv0 = &sWv[wave * 32][0];      f16* lWv1 = &sWv[wave * 32 + 16][0];

    f32x4 zero4 = {0.f, 0.f, 0.f, 0.f};
    f32x4 accQ[2][4], accKi[2][4], accKs[2][4], accVi[2][4], accVs[2][4];
    #pragma unroll
    for (int i = 0; i < 2; i++)
        #pragma unroll
        for (int j = 0; j < 4; j++) {
            accQ[i][j] = zero4; accKi[i][j] = zero4; accKs[i][j] = zero4;
            accVi[i][j] = zero4; accVs[i][j] = zero4;
        }

    for (int kk = 0; kk < E_; kk += BK) {
        gload16(gAi + kk, lAi);
        gload16(gAs + kk, lAs);
        gload16(gWq + kk, lWq0);
        gload16(gWq + wskip + kk, lWq1);
        gload16(gWk + kk, lWk0);
        gload16(gWk + wskip + kk, lWk1);
        gload16(gWv + kk, lWv0);
        gload16(gWv + wskip + kk, lWv1);
        __syncthreads();   // drains vmcnt -> tile resident

        f16x8 aI[2], aS[2], bF[4];
        #pragma unroll
        for (int fr = 0; fr < 2; fr++) {
            aI[fr] = *(const f16x8*)&sAi[wr * 32 + fr * 16 + l16][rc];
            aS[fr] = *(const f16x8*)&sAs[wr * 32 + fr * 16 + l16][rc];
        }
        // Q
        #pragma unroll
        for (int fc = 0; fc < 4; fc++)
            bF[fc] = *(const f16x8*)&sWq[wc * 64 + fc * 16 + l16][rc];
        #pragma unroll
        for (int fr = 0; fr < 2; fr++)
            #pragma unroll
            for (int fc = 0; fc < 4; fc++)
                accQ[fr][fc] = __builtin_amdgcn_mfma_f32_16x16x32_f16(aI[fr], bF[fc], accQ[fr][fc], 0, 0, 0);
        // K (both modalities share B-frag)
        #pragma unroll
        for (int fc = 0; fc < 4; fc++)
            bF[fc] = *(const f16x8*)&sWk[wc * 64 + fc * 16 + l16][rc];
        #pragma unroll
        for (int fr = 0; fr < 2; fr++)
            #pragma unroll
            for (int fc = 0; fc < 4; fc++) {
                accKi[fr][fc] = __builtin_amdgcn_mfma_f32_16x16x32_f16(aI[fr], bF[fc], accKi[fr][fc], 0, 0, 0);
                accKs[fr][fc] = __builtin_amdgcn_mfma_f32_16x16x32_f16(aS[fr], bF[fc], accKs[fr][fc], 0, 0, 0);
            }
        // V (both modalities share B-frag)
        #pragma unroll
        for (int fc = 0; fc < 4; fc++)
            bF[fc] = *(const f16x8*)&sWv[wc * 64 + fc * 16 + l16][rc];
        #pragma unroll
        for (int fr = 0; fr < 2; fr++)
            #pragma unroll
            for (int fc = 0; fc < 4; fc++) {
                accVi[fr][fc] = __builtin_amdgcn_mfma_f32_16x16x32_f16(aI[fr], bF[fc], accVi[fr][fc], 0, 0, 0);
                accVs[fr][fc] = __builtin_amdgcn_mfma_f32_16x16x32_f16(aS[fr], bF[fc], accVs[fr][fc], 0, 0, 0);
            }
        __syncthreads();   // protect LDS tile until all waves done reading
    }

    // biases on score paths (zero in practice but correct in general)
    #pragma unroll
    for (int fc = 0; fc < 4; fc++) {
        int col = col0 + wc * 64 + fc * 16 + l16;
        float bqv = bq[col], bkv = bk[col];
        #pragma unroll
        for (int fr = 0; fr < 2; fr++)
            #pragma unroll
            for (int e = 0; e < 4; e++) {
                accQ[fr][fc][e]  += bqv;
                accKi[fr][fc][e] += bkv;
                accKs[fr][fc][e] += bkv;
            }
    }

    // scores: per-row dot(q,k) over this head's 128 cols
    // C layout: col = lane&15, row = (lane>>4)*4 + e (within 16x16 frag)
    #pragma unroll
    for (int fr = 0; fr < 2; fr++)
        #pragma unroll
        for (int e = 0; e < 4; e++) {
            float d0 = 0.f, d1 = 0.f;
            #pragma unroll
            for (int fc = 0; fc < 4; fc++) {
                d0 += accQ[fr][fc][e] * accKi[fr][fc][e];
                d1 += accQ[fr][fc][e] * accKs[fr][fc][e];
            }
            #pragma unroll
            for (int m = 1; m < 16; m <<= 1) {
                d0 += __shfl_xor(d0, m, 64);
                d1 += __shfl_xor(d1, m, 64);
            }
            if (l16 == 0) {
                int row = wr * 32 + fr * 16 + lq * 4 + e;
                sdot[0][row][wc] = d0;
                sdot[1][row][wc] = d1;
            }
        }
    __syncthreads();
    if (tid < 64) {
        const float scale = 0.088388347648318447f;  // 1/sqrt(128)
        float s0 = (sdot[0][tid][0] + sdot[0][tid][1]) * scale;
        float s1 = (sdot[1][tid][0] + sdot[1][tid][1]) * scale;
        sa0[tid] = 1.0f / (1.0f + expf(s1 - s0));
    }
    __syncthreads();

    // ctx = a0*Vimg + a1*Vsig + bv, written f16
    #pragma unroll
    for (int fc = 0; fc < 4; fc++) {
        int col = col0 + wc * 64 + fc * 16 + l16;
        float bvv = bv[col];
        #pragma unroll
        for (int fr = 0; fr < 2; fr++)
            #pragma unroll
            for (int e = 0; e < 4; e++) {
                int row = wr * 32 + fr * 16 + lq * 4 + e;
                float a0 = sa0[row];
                float v  = a0 * accVi[fr][fc][e] + (1.0f - a0) * accVs[fr][fc][e] + bvv;
                ctx[(size_t)(row0 + row) * E_ + col] = (f16)v;
            }
    }
}

// ---------------- out projection: ctx @ Wo^T + bo + residual -> f32 ----------------
// grid (B/128, E/128), 256 threads, 4 waves each 64x64 (4x4 frags).
// Double-buffered 2-phase: issue next-tile gload_lds before current ds_read+MFMA;
// one __syncthreads per K-step (drains this wave's prefetch vmcnt + syncs).
__global__ __launch_bounds__(256) void out_proj_kernel(
    const f16* __restrict__ A, const f16* __restrict__ Wo, const float* __restrict__ bo,
    const float* __restrict__ resid, float* __restrict__ out)
{
    __shared__ f16 sA[2][128][BK];
    __shared__ f16 sB[2][128][BK];
    const int tid  = threadIdx.x;
    const int lane = tid & 63;
    const int wave = tid >> 6;
    const int wr = wave >> 1, wc = wave & 1;
    const int l16 = lane & 15, lq = lane >> 4;
    const int row0 = blockIdx.x * 128;
    const int col0 = blockIdx.y * 128;

    const int lr = lane >> 2;
    const int lc = ((lane & 3) ^ ((lane >> 3) & 3)) * 8;   // swizzled source chunk
    const int rc = (lq ^ ((l16 >> 1) & 3)) * 8;            // swizzled read col

    const f16* gA0 = A  + (size_t)(row0 + wave * 32 + lr) * E_ + lc;
    const f16* gB0 = Wo + (size_t)(col0 + wave * 32 + lr) * E_ + lc;
    const size_t wskip = (size_t)16 * E_;

    f32x4 zero4 = {0.f, 0.f, 0.f, 0.f};
    f32x4 acc[4][4];
    #pragma unroll
    for (int i = 0; i < 4; i++)
        #pragma unroll
        for (int j = 0; j < 4; j++) acc[i][j] = zero4;

    auto stage = [&](int buf, int kk) {
        gload16(gA0 + kk,         &sA[buf][wave * 32][0]);
        gload16(gA0 + wskip + kk, &sA[buf][wave * 32 + 16][0]);
        gload16(gB0 + kk,         &sB[buf][wave * 32][0]);
        gload16(gB0 + wskip + kk, &sB[buf][wave * 32 + 16][0]);
    };

    stage(0, 0);
    __syncthreads();

    const int NT = E_ / BK;   // 32
    for (int t = 0; t < NT; ++t) {
        const int cur = t & 1;
        if (t + 1 < NT) stage(cur ^ 1, (t + 1) * BK);

        f16x8 aF[4], bF[4];
        #pragma unroll
        for (int f = 0; f < 4; f++) {
            aF[f] = *(const f16x8*)&sA[cur][wr * 64 + f * 16 + l16][rc];
            bF[f] = *(const f16x8*)&sB[cur][wc * 64 + f * 16 + l16][rc];
        }
        #pragma unroll
        for (int fr = 0; fr < 4; fr++)
            #pragma unroll
            for (int fc = 0; fc < 4; fc++)
                acc[fr][fc] = __builtin_amdgcn_mfma_f32_16x16x32_f16(aF[fr], bF[fc], acc[fr][fc], 0, 0, 0);
        __syncthreads();
    }

    #pragma unroll
    for (int fc = 0; fc < 4; fc++) {
        int col = col0 + wc * 64 + fc * 16 + l16;
        float bov = bo[col];
        #pragma unroll
        for (int fr = 0; fr < 4; fr++)
            #pragma unroll
            for (int e = 0; e < 4; e++) {
                int row = row0 + wr * 64 + fr * 16 + lq * 4 + e;
                out[(size_t)row * E_ + col] = acc[fr][fc][e] + bov + resid[(size_t)row * E_ + col];
            }
    }
}

// ---------------- in-place LayerNorm over E=1024 ----------------
__global__ __launch_bounds__(256) void ln_kernel(
    float* __restrict__ x, const float* __restrict__ gamma,
    const float* __restrict__ beta, float* __restrict__ out)
{
    const int row = blockIdx.x;
    const int tid = threadIdx.x;
    const float4* xr = (const float4*)(x + (size_t)row * E_);
    float4 v = xr[tid];
    float s  = v.x + v.y + v.z + v.w;
    float s2 = v.x * v.x + v.y * v.y + v.z * v.z + v.w * v.w;
    #pragma unroll
    for (int m = 1; m < 64; m <<= 1) {
        s  += __shfl_xor(s, m, 64);
        s2 += __shfl_xor(s2, m, 64);
    }
    __shared__ float red[8];
    int wv = tid >> 6, ln = tid & 63;
    if (ln == 0) { red[wv] = s; red[4 + wv] = s2; }
    __syncthreads();
    s  = red[0] + red[1] + red[2] + red[3];
    s2 = red[4] + red[5] + red[6] + red[7];
    float mu  = s * (1.0f / E_);
    float var = s2 * (1.0f / E_) - mu * mu;
    float r   = rsqrtf(var + 1e-5f);
    float4 g  = ((const float4*)gamma)[tid];
    float4 bb = ((const float4*)beta)[tid];
    float4 o;
    o.x = (v.x - mu) * r * g.x + bb.x;
    o.y = (v.y - mu) * r * g.y + bb.y;
    o.z = (v.z - mu) * r * g.z + bb.z;
    o.w = (v.w - mu) * r * g.w + bb.w;
    ((float4*)(out + (size_t)row * E_))[tid] = o;
}

extern "C" void kernel_launch(void* const* d_in, const int* in_sizes, int n_in,
                              void* d_out, int out_size, void* d_ws, size_t ws_size,
                              hipStream_t stream)
{
    (void)in_sizes; (void)n_in; (void)out_size; (void)ws_size;
    const float* image  = (const float*)d_in[0];
    const float* signal = (const float*)d_in[1];
    const float* Wq = (const float*)d_in[2];
    const float* Wk = (const float*)d_in[3];
    const float* Wv = (const float*)d_in[4];
    const float* bq = (const float*)d_in[5];
    const float* bk = (const float*)d_in[6];
    const float* bv = (const float*)d_in[7];
    const float* Wo = (const float*)d_in[8];
    const float* bo = (const float*)d_in[9];
    const float* gamma = (const float*)d_in[10];
    const float* beta  = (const float*)d_in[11];
    float* out = (float*)d_out;

    char* ws = (char*)d_ws;
    f16* Xi16 = (f16*)(ws);                            // 32 MB
    f16* Xs16 = (f16*)(ws + 32ull * 1024 * 1024);      // 32 MB
    f16* Wq16 = (f16*)(ws + 64ull * 1024 * 1024);      // 2 MB
    f16* Wk16 = (f16*)(ws + 66ull * 1024 * 1024);      // 2 MB
    f16* Wv16 = (f16*)(ws + 68ull * 1024 * 1024);      // 2 MB
    f16* Wo16 = (f16*)(ws + 70ull * 1024 * 1024);      // 2 MB
    f16* ctx  = (f16*)(ws + 72ull * 1024 * 1024);      // 32 MB  (total 104 MB)

    const int nBE4 = B_ * E_ / 4;   // 4194304
    const int nEE4 = E_ * E_ / 4;   // 262144
    dim3 gX(nBE4 / 256, 2);
    cvt2_kernel<<<gX, 256, 0, stream>>>((const float4*)image, (const float4*)signal,
                                        (ushort4*)Xi16, (ushort4*)Xs16, nBE4);
    dim3 gW(nEE4 / 256, 4);
    cvt4_kernel<<<gW, 256, 0, stream>>>((const float4*)Wq, (const float4*)Wk,
                                        (const float4*)Wv, (const float4*)Wo,
                                        (ushort4*)Wq16, (ushort4*)Wk16,
                                        (ushort4*)Wv16, (ushort4*)Wo16, nEE4);

    dim3 g2(B_ / 64, H_);
    qkv_attn_kernel<<<g2, 256, 0, stream>>>(Xi16, Xs16, Wq16, Wk16, Wv16, bq, bk, bv, ctx);

    dim3 g4(B_ / 128, E_ / 128);
    out_proj_kernel<<<g4, 256, 0, stream>>>(ctx, Wo16, bo, image, out);

    ln_kernel<<<B_, 256, 0, stream>>>(out, gamma, beta, out);
}